// Round 1
// baseline (340.729 us; speedup 1.0000x reference)
//
#include <hip/hip_runtime.h>
#include <hip/hip_bf16.h>
#include <stdint.h>
#include <type_traits>

// DispersiveLoss: B=1024 rows, D=65536. loss = 0.25*log(mean_{i!=j} exp(-|zi_n - zj_n|^2))
// Strategy: bf16 cast of raw z (normalization folded into epilogue via inv_norm),
// split-K bf16 MFMA Gram GEMM into 8 fp32 slabs, then fused exp-sum reduction.

#define NROWS 1024
#define KDIM  65536
#define NSPLIT 8

typedef __attribute__((ext_vector_type(8))) short  s16x8;
typedef __attribute__((ext_vector_type(4))) float  f32x4;

__device__ __forceinline__ ushort f2bf(float f) {
  uint32_t u = __float_as_uint(f);
  return (ushort)((u + 0x7fffu + ((u >> 16) & 1u)) >> 16);  // RNE bf16
}

// ---- fused: row sum-of-squares -> inv_norm, plus raw fp32 -> bf16 cast ----
__global__ void k_prep(const float* __restrict__ z, ushort* __restrict__ zb,
                       float* __restrict__ inv_norm) {
  const int row = blockIdx.x;
  const float4* zr = (const float4*)(z + (size_t)row * KDIM);
  ushort* br = zb + (size_t)row * KDIM;
  float ss = 0.f;
  for (int i = threadIdx.x; i < KDIM / 4; i += blockDim.x) {
    const float4 v = zr[i];
    ss += v.x * v.x + v.y * v.y + v.z * v.z + v.w * v.w;
    ushort4 o;
    o.x = f2bf(v.x); o.y = f2bf(v.y); o.z = f2bf(v.z); o.w = f2bf(v.w);
    ((ushort4*)br)[i] = o;
  }
  for (int off = 32; off; off >>= 1) ss += __shfl_down(ss, off, 64);
  __shared__ float part[4];
  const int lane = threadIdx.x & 63, w = threadIdx.x >> 6;
  if (lane == 0) part[w] = ss;
  __syncthreads();
  if (threadIdx.x == 0) {
    const float t = part[0] + part[1] + part[2] + part[3];
    inv_norm[row] = 1.f / fmaxf(sqrtf(t), 1e-12f);
  }
}

// ---- fallback (no bf16 copy fits): norms only ----
__global__ void k_rownorm(const float* __restrict__ z, float* __restrict__ inv_norm) {
  const int row = blockIdx.x;
  const float4* zr = (const float4*)(z + (size_t)row * KDIM);
  float ss = 0.f;
  for (int i = threadIdx.x; i < KDIM / 4; i += blockDim.x) {
    const float4 v = zr[i];
    ss += v.x * v.x + v.y * v.y + v.z * v.z + v.w * v.w;
  }
  for (int off = 32; off; off >>= 1) ss += __shfl_down(ss, off, 64);
  __shared__ float part[4];
  const int lane = threadIdx.x & 63, w = threadIdx.x >> 6;
  if (lane == 0) part[w] = ss;
  __syncthreads();
  if (threadIdx.x == 0) {
    const float t = part[0] + part[1] + part[2] + part[3];
    inv_norm[row] = 1.f / fmaxf(sqrtf(t), 1e-12f);
  }
}

// ---- split-K Gram GEMM: C_tile += A_rows * A_rows^T over K chunk ----
// 128x128 tile, BK=32, 256 threads = 4 waves (2x2), each wave 64x64 via 4x4
// mfma_f32_16x16x32_bf16 fragments. Double-buffered LDS, global_load_lds w=16.
template <bool BF16SRC, bool ATOMIC>
__global__ __launch_bounds__(256, 2)
void k_gram(const void* __restrict__ src, float* __restrict__ gout, int kPerSplit) {
  constexpr int BK = 32;
  using ST = typename std::conditional<BF16SRC, ushort, float>::type;
  __shared__ __align__(16) ST lA[2][128 * BK];
  __shared__ __align__(16) ST lB[2][128 * BK];

  const int tid  = threadIdx.x;
  const int lane = tid & 63;
  const int wid  = tid >> 6;
  const int wr   = wid >> 1, wc = wid & 1;
  const int tm = blockIdx.x >> 3, tn = blockIdx.x & 7;
  const size_t k0base = (size_t)blockIdx.y * kPerSplit;

  const ST* gA = (const ST*)src + (size_t)(tm * 128) * KDIM + k0base;
  const ST* gB = (const ST*)src + (size_t)(tn * 128) * KDIM + k0base;

  f32x4 acc[4][4];
#pragma unroll
  for (int i = 0; i < 4; i++)
#pragma unroll
    for (int j = 0; j < 4; j++) acc[i][j] = (f32x4){0.f, 0.f, 0.f, 0.f};

  const int NT = kPerSplit / BK;

  auto stage = [&](int buf, int t) {
    const int kc = t * BK;
    if constexpr (BF16SRC) {
#pragma unroll
      for (int q = 0; q < 2; q++) {
        const int r = (tid >> 2) + q * 64;
        const int c = (tid & 3) * 8;
        __builtin_amdgcn_global_load_lds(
            (const __attribute__((address_space(1))) void*)(gA + (size_t)r * KDIM + kc + c),
            (__attribute__((address_space(3))) void*)(&lA[buf][r * BK + c]), 16, 0, 0);
        __builtin_amdgcn_global_load_lds(
            (const __attribute__((address_space(1))) void*)(gB + (size_t)r * KDIM + kc + c),
            (__attribute__((address_space(3))) void*)(&lB[buf][r * BK + c]), 16, 0, 0);
      }
    } else {
#pragma unroll
      for (int q = 0; q < 4; q++) {
        const int r = (tid >> 3) + q * 32;
        const int c = (tid & 7) * 4;
        __builtin_amdgcn_global_load_lds(
            (const __attribute__((address_space(1))) void*)(gA + (size_t)r * KDIM + kc + c),
            (__attribute__((address_space(3))) void*)(&lA[buf][r * BK + c]), 16, 0, 0);
        __builtin_amdgcn_global_load_lds(
            (const __attribute__((address_space(1))) void*)(gB + (size_t)r * KDIM + kc + c),
            (__attribute__((address_space(3))) void*)(&lB[buf][r * BK + c]), 16, 0, 0);
      }
    }
  };

  auto loadfrag = [&](const ST* p) -> s16x8 {
    if constexpr (BF16SRC) {
      return *(const s16x8*)p;
    } else {
      const float4 u0 = *(const float4*)p;
      const float4 u1 = *(const float4*)(p + 4);
      s16x8 s;
      s[0] = (short)f2bf(u0.x); s[1] = (short)f2bf(u0.y);
      s[2] = (short)f2bf(u0.z); s[3] = (short)f2bf(u0.w);
      s[4] = (short)f2bf(u1.x); s[5] = (short)f2bf(u1.y);
      s[6] = (short)f2bf(u1.z); s[7] = (short)f2bf(u1.w);
      return s;
    }
  };

  stage(0, 0);
  int cur = 0;
  for (int t = 0; t < NT; ++t) {
    __syncthreads();                    // drains vmcnt: buf[cur] staged, prev reads done
    if (t + 1 < NT) stage(cur ^ 1, t + 1);  // overlap next-tile loads with compute
    const int rA = wr * 64 + (lane & 15);
    const int rB = wc * 64 + (lane & 15);
    const int cK = (lane >> 4) * 8;
    s16x8 a[4], b[4];
#pragma unroll
    for (int i = 0; i < 4; i++) {
      a[i] = loadfrag(&lA[cur][(rA + i * 16) * BK + cK]);
      b[i] = loadfrag(&lB[cur][(rB + i * 16) * BK + cK]);
    }
#pragma unroll
    for (int i = 0; i < 4; i++)
#pragma unroll
      for (int j = 0; j < 4; j++)
        acc[i][j] = __builtin_amdgcn_mfma_f32_16x16x32_bf16(a[i], b[j], acc[i][j], 0, 0, 0);
    cur ^= 1;
  }

  // epilogue: C/D layout (verified m89): col = lane&15, row = (lane>>4)*4 + reg
  float* out = ATOMIC ? gout : gout + (size_t)blockIdx.y * ((size_t)NROWS * NROWS);
  const int rbase = tm * 128 + wr * 64 + (lane >> 4) * 4;
  const int cbase = tn * 128 + wc * 64 + (lane & 15);
#pragma unroll
  for (int i = 0; i < 4; i++)
#pragma unroll
    for (int j = 0; j < 4; j++)
#pragma unroll
      for (int r = 0; r < 4; r++) {
        const int row = rbase + i * 16 + r;
        const int col = cbase + j * 16;
        if constexpr (ATOMIC)
          atomicAdd(&out[(size_t)row * NROWS + col], acc[i][j][r]);
        else
          out[(size_t)row * NROWS + col] = acc[i][j][r];
      }
}

// ---- diag_n[i] = (sum_s slab[s][i,i]) * inv_i^2 ----
__global__ void k_diag(const float* __restrict__ gbuf, const float* __restrict__ inv_norm,
                       float* __restrict__ diag, int nslab) {
  const int i = blockIdx.x * 256 + threadIdx.x;
  float s = 0.f;
  for (int q = 0; q < nslab; ++q)
    s += gbuf[(size_t)q * ((size_t)NROWS * NROWS) + (size_t)i * (NROWS + 1)];
  const float w = inv_norm[i];
  diag[i] = s * w * w;
}

// ---- sum_{i!=j} exp(-max(d_i + d_j - 2 g_ij inv_i inv_j, 0)) ----
__global__ void k_expsum(const float* __restrict__ gbuf, const float* __restrict__ inv_norm,
                         const float* __restrict__ diag, float* __restrict__ accum, int nslab) {
  const int gid = blockIdx.x * 256 + threadIdx.x;
  const int e0 = gid * 4;
  const int i  = e0 >> 10;
  const int j0 = e0 & 1023;
  float gx = 0.f, gy = 0.f, gz = 0.f, gw = 0.f;
  for (int q = 0; q < nslab; ++q) {
    const float4 t = *(const float4*)(gbuf + (size_t)q * ((size_t)NROWS * NROWS) + e0);
    gx += t.x; gy += t.y; gz += t.z; gw += t.w;
  }
  const float wi = inv_norm[i];
  const float di = diag[i];
  const float4 wj = *(const float4*)(inv_norm + j0);
  const float4 dj = *(const float4*)(diag + j0);
  float s = 0.f;
  float gn, d2;
  gn = gx * wi * wj.x; d2 = fmaxf(di + dj.x - 2.f * gn, 0.f); if (i != j0 + 0) s += expf(-d2);
  gn = gy * wi * wj.y; d2 = fmaxf(di + dj.y - 2.f * gn, 0.f); if (i != j0 + 1) s += expf(-d2);
  gn = gz * wi * wj.z; d2 = fmaxf(di + dj.z - 2.f * gn, 0.f); if (i != j0 + 2) s += expf(-d2);
  gn = gw * wi * wj.w; d2 = fmaxf(di + dj.w - 2.f * gn, 0.f); if (i != j0 + 3) s += expf(-d2);
  for (int off = 32; off; off >>= 1) s += __shfl_down(s, off, 64);
  __shared__ float part[4];
  const int lane = threadIdx.x & 63, w = threadIdx.x >> 6;
  if (lane == 0) part[w] = s;
  __syncthreads();
  if (threadIdx.x == 0) atomicAdd(accum, part[0] + part[1] + part[2] + part[3]);
}

__global__ void k_final(const float* __restrict__ accum, float* __restrict__ out) {
  out[0] = 0.25f * logf(accum[0] / ((float)NROWS * (float)(NROWS - 1)));
}

extern "C" void kernel_launch(void* const* d_in, const int* in_sizes, int n_in,
                              void* d_out, int out_size, void* d_ws, size_t ws_size,
                              hipStream_t stream) {
  const float* z = (const float*)d_in[0];
  float* out = (float*)d_out;
  char* ws = (char*)d_ws;

  float* inv_norm = (float*)(ws);           // 4 KB
  float* diag     = (float*)(ws + 4096);    // 4 KB
  float* accum    = (float*)(ws + 8192);    // 4 B
  float* gbuf     = (float*)(ws + 65536);   // slabs

  const size_t GB1 = (size_t)NROWS * NROWS * sizeof(float);  // 4 MB per slab
  const size_t BFB = (size_t)NROWS * KDIM * sizeof(ushort);  // 128 MB bf16 copy

  bool bf16src, atomic;
  int nslab;
  if (ws_size >= 65536 + 8 * GB1 + BFB)      { bf16src = true;  atomic = false; nslab = 8; }
  else if (ws_size >= 65536 + 1 * GB1 + BFB) { bf16src = true;  atomic = true;  nslab = 1; }
  else if (ws_size >= 65536 + 8 * GB1)       { bf16src = false; atomic = false; nslab = 8; }
  else                                       { bf16src = false; atomic = true;  nslab = 1; }

  hipMemsetAsync(accum, 0, sizeof(float), stream);
  if (atomic) hipMemsetAsync(gbuf, 0, GB1, stream);

  const void* gsrc = (const void*)z;
  if (bf16src) {
    ushort* zb = (ushort*)(ws + 65536 + (size_t)nslab * GB1);
    k_prep<<<NROWS, 256, 0, stream>>>(z, zb, inv_norm);
    gsrc = (const void*)zb;
  } else {
    k_rownorm<<<NROWS, 256, 0, stream>>>(z, inv_norm);
  }

  const int kPerSplit = KDIM / NSPLIT;  // 8192
  dim3 grid(64, NSPLIT);
  if (bf16src && !atomic)      k_gram<true,  false><<<grid, 256, 0, stream>>>(gsrc, gbuf, kPerSplit);
  else if (bf16src && atomic)  k_gram<true,  true ><<<grid, 256, 0, stream>>>(gsrc, gbuf, kPerSplit);
  else if (!atomic)            k_gram<false, false><<<grid, 256, 0, stream>>>(gsrc, gbuf, kPerSplit);
  else                         k_gram<false, true ><<<grid, 256, 0, stream>>>(gsrc, gbuf, kPerSplit);

  k_diag<<<NROWS / 256, 256, 0, stream>>>(gbuf, inv_norm, diag, nslab);
  k_expsum<<<(NROWS * NROWS / 4) / 256, 256, 0, stream>>>(gbuf, inv_norm, diag, accum, nslab);
  k_final<<<1, 1, 0, stream>>>(accum, out);
}

// Round 2
// 325.556 us; speedup vs baseline: 1.0466x; 1.0466x over previous
//
#include <hip/hip_runtime.h>
#include <hip/hip_bf16.h>
#include <stdint.h>
#include <type_traits>

// DispersiveLoss: B=1024 rows, D=65536. loss = 0.25*log(mean_{i!=j} exp(-|zi_n - zj_n|^2))
// R2: symmetric Gram (only tm<=tn tiles, 36/64), split-K=32 for occupancy
// (1152 blocks, ~4.5/CU vs previous 2/CU), atomic 8-slab accumulation.

#define NROWS 1024
#define KDIM  65536
#define NSPLIT 32
#define NTILE 36   // 8*9/2 upper-triangle 128x128 tiles

typedef __attribute__((ext_vector_type(8))) short  s16x8;
typedef __attribute__((ext_vector_type(4))) float  f32x4;

__device__ __forceinline__ ushort f2bf(float f) {
  uint32_t u = __float_as_uint(f);
  return (ushort)((u + 0x7fffu + ((u >> 16) & 1u)) >> 16);  // RNE bf16
}

// ---- fused: row sum-of-squares -> inv_norm, plus raw fp32 -> bf16 cast ----
__global__ void k_prep(const float* __restrict__ z, ushort* __restrict__ zb,
                       float* __restrict__ inv_norm) {
  const int row = blockIdx.x;
  const float4* zr = (const float4*)(z + (size_t)row * KDIM);
  ushort* br = zb + (size_t)row * KDIM;
  float ss = 0.f;
  for (int i = threadIdx.x; i < KDIM / 4; i += blockDim.x) {
    const float4 v = zr[i];
    ss += v.x * v.x + v.y * v.y + v.z * v.z + v.w * v.w;
    ushort4 o;
    o.x = f2bf(v.x); o.y = f2bf(v.y); o.z = f2bf(v.z); o.w = f2bf(v.w);
    ((ushort4*)br)[i] = o;
  }
  for (int off = 32; off; off >>= 1) ss += __shfl_down(ss, off, 64);
  __shared__ float part[4];
  const int lane = threadIdx.x & 63, w = threadIdx.x >> 6;
  if (lane == 0) part[w] = ss;
  __syncthreads();
  if (threadIdx.x == 0) {
    const float t = part[0] + part[1] + part[2] + part[3];
    inv_norm[row] = 1.f / fmaxf(sqrtf(t), 1e-12f);
  }
}

__global__ void k_rownorm(const float* __restrict__ z, float* __restrict__ inv_norm) {
  const int row = blockIdx.x;
  const float4* zr = (const float4*)(z + (size_t)row * KDIM);
  float ss = 0.f;
  for (int i = threadIdx.x; i < KDIM / 4; i += blockDim.x) {
    const float4 v = zr[i];
    ss += v.x * v.x + v.y * v.y + v.z * v.z + v.w * v.w;
  }
  for (int off = 32; off; off >>= 1) ss += __shfl_down(ss, off, 64);
  __shared__ float part[4];
  const int lane = threadIdx.x & 63, w = threadIdx.x >> 6;
  if (lane == 0) part[w] = ss;
  __syncthreads();
  if (threadIdx.x == 0) {
    const float t = part[0] + part[1] + part[2] + part[3];
    inv_norm[row] = 1.f / fmaxf(sqrtf(t), 1e-12f);
  }
}

// ---- split-K symmetric Gram: upper-triangle 128x128 tiles only ----
// 256 threads = 4 waves (2x2), each wave 64x64 via 4x4 mfma_f32_16x16x32_bf16.
// Double-buffered LDS, global_load_lds width=16. Epilogue: atomicAdd into
// slab (blockIdx.y & 7); 4 contributors per cell across 32 K-splits.
template <bool BF16SRC>
__global__ __launch_bounds__(256, 4)
void k_gram(const void* __restrict__ src, float* __restrict__ gout,
            int kPerSplit, int nslab) {
  constexpr int BK = 32;
  using ST = typename std::conditional<BF16SRC, ushort, float>::type;
  __shared__ __align__(16) ST lA[2][128 * BK];
  __shared__ __align__(16) ST lB[2][128 * BK];

  const int tid  = threadIdx.x;
  const int lane = tid & 63;
  const int wid  = tid >> 6;
  const int wr   = wid >> 1, wc = wid & 1;

  // map blockIdx.x in [0,36) -> upper-triangle tile (tm, tn), tm <= tn
  int tm = 0, r = blockIdx.x;
  while (r >= 8 - tm) { r -= 8 - tm; ++tm; }
  const int tn = tm + r;

  const size_t k0base = (size_t)blockIdx.y * kPerSplit;
  const ST* gA = (const ST*)src + (size_t)(tm * 128) * KDIM + k0base;
  const ST* gB = (const ST*)src + (size_t)(tn * 128) * KDIM + k0base;

  f32x4 acc[4][4];
#pragma unroll
  for (int i = 0; i < 4; i++)
#pragma unroll
    for (int j = 0; j < 4; j++) acc[i][j] = (f32x4){0.f, 0.f, 0.f, 0.f};

  const int NT = kPerSplit / BK;

  auto stage = [&](int buf, int t) {
    const int kc = t * BK;
    if constexpr (BF16SRC) {
#pragma unroll
      for (int q = 0; q < 2; q++) {
        const int rr = (tid >> 2) + q * 64;
        const int cc = (tid & 3) * 8;
        __builtin_amdgcn_global_load_lds(
            (const __attribute__((address_space(1))) void*)(gA + (size_t)rr * KDIM + kc + cc),
            (__attribute__((address_space(3))) void*)(&lA[buf][rr * BK + cc]), 16, 0, 0);
        __builtin_amdgcn_global_load_lds(
            (const __attribute__((address_space(1))) void*)(gB + (size_t)rr * KDIM + kc + cc),
            (__attribute__((address_space(3))) void*)(&lB[buf][rr * BK + cc]), 16, 0, 0);
      }
    } else {
#pragma unroll
      for (int q = 0; q < 4; q++) {
        const int rr = (tid >> 3) + q * 32;
        const int cc = (tid & 7) * 4;
        __builtin_amdgcn_global_load_lds(
            (const __attribute__((address_space(1))) void*)(gA + (size_t)rr * KDIM + kc + cc),
            (__attribute__((address_space(3))) void*)(&lA[buf][rr * BK + cc]), 16, 0, 0);
        __builtin_amdgcn_global_load_lds(
            (const __attribute__((address_space(1))) void*)(gB + (size_t)rr * KDIM + kc + cc),
            (__attribute__((address_space(3))) void*)(&lB[buf][rr * BK + cc]), 16, 0, 0);
      }
    }
  };

  auto loadfrag = [&](const ST* p) -> s16x8 {
    if constexpr (BF16SRC) {
      return *(const s16x8*)p;
    } else {
      const float4 u0 = *(const float4*)p;
      const float4 u1 = *(const float4*)(p + 4);
      s16x8 s;
      s[0] = (short)f2bf(u0.x); s[1] = (short)f2bf(u0.y);
      s[2] = (short)f2bf(u0.z); s[3] = (short)f2bf(u0.w);
      s[4] = (short)f2bf(u1.x); s[5] = (short)f2bf(u1.y);
      s[6] = (short)f2bf(u1.z); s[7] = (short)f2bf(u1.w);
      return s;
    }
  };

  stage(0, 0);
  int cur = 0;
  for (int t = 0; t < NT; ++t) {
    __syncthreads();                        // drains vmcnt: buf[cur] ready
    if (t + 1 < NT) stage(cur ^ 1, t + 1);  // prefetch overlaps compute
    const int rA = wr * 64 + (lane & 15);
    const int rB = wc * 64 + (lane & 15);
    const int cK = (lane >> 4) * 8;
    s16x8 a[4], b[4];
#pragma unroll
    for (int i = 0; i < 4; i++) {
      a[i] = loadfrag(&lA[cur][(rA + i * 16) * BK + cK]);
      b[i] = loadfrag(&lB[cur][(rB + i * 16) * BK + cK]);
    }
#pragma unroll
    for (int i = 0; i < 4; i++)
#pragma unroll
      for (int j = 0; j < 4; j++)
        acc[i][j] = __builtin_amdgcn_mfma_f32_16x16x32_bf16(a[i], b[j], acc[i][j], 0, 0, 0);
    cur ^= 1;
  }

  // epilogue: C/D layout (verified m89): col = lane&15, row = (lane>>4)*4 + reg
  float* out = gout + (size_t)(blockIdx.y & (nslab - 1)) * ((size_t)NROWS * NROWS);
  const int rbase = tm * 128 + wr * 64 + (lane >> 4) * 4;
  const int cbase = tn * 128 + wc * 64 + (lane & 15);
#pragma unroll
  for (int i = 0; i < 4; i++)
#pragma unroll
    for (int j = 0; j < 4; j++)
#pragma unroll
      for (int rg = 0; rg < 4; rg++) {
        const int row = rbase + i * 16 + rg;
        const int col = cbase + j * 16;
        atomicAdd(&out[(size_t)row * NROWS + col], acc[i][j][rg]);
      }
}

// ---- diag_n[i] = (sum_s slab[s][i,i]) * inv_i^2  (~1.0) ----
__global__ void k_diag(const float* __restrict__ gbuf, const float* __restrict__ inv_norm,
                       float* __restrict__ diag, int nslab) {
  const int i = blockIdx.x * 256 + threadIdx.x;
  float s = 0.f;
  for (int q = 0; q < nslab; ++q)
    s += gbuf[(size_t)q * ((size_t)NROWS * NROWS) + (size_t)i * (NROWS + 1)];
  const float w = inv_norm[i];
  diag[i] = s * w * w;
}

// ---- accum = sum_{i<j} exp(-max(d_i + d_j - 2 g_ij inv_i inv_j, 0)) ----
// slabs hold only the upper triangle (and diagonal tiles); lower cells are 0
// and are masked off by the i<j condition.
__global__ void k_expsum(const float* __restrict__ gbuf, const float* __restrict__ inv_norm,
                         const float* __restrict__ diag, float* __restrict__ accum, int nslab) {
  const int gid = blockIdx.x * 256 + threadIdx.x;
  const int e0 = gid * 4;
  const int i  = e0 >> 10;
  const int j0 = e0 & 1023;
  float gx = 0.f, gy = 0.f, gz = 0.f, gw = 0.f;
  for (int q = 0; q < nslab; ++q) {
    const float4 t = *(const float4*)(gbuf + (size_t)q * ((size_t)NROWS * NROWS) + e0);
    gx += t.x; gy += t.y; gz += t.z; gw += t.w;
  }
  const float wi = inv_norm[i];
  const float di = diag[i];
  const float4 wj = *(const float4*)(inv_norm + j0);
  const float4 dj = *(const float4*)(diag + j0);
  float s = 0.f;
  float gn, d2;
  gn = gx * wi * wj.x; d2 = fmaxf(di + dj.x - 2.f * gn, 0.f); if (i < j0 + 0) s += expf(-d2);
  gn = gy * wi * wj.y; d2 = fmaxf(di + dj.y - 2.f * gn, 0.f); if (i < j0 + 1) s += expf(-d2);
  gn = gz * wi * wj.z; d2 = fmaxf(di + dj.z - 2.f * gn, 0.f); if (i < j0 + 2) s += expf(-d2);
  gn = gw * wi * wj.w; d2 = fmaxf(di + dj.w - 2.f * gn, 0.f); if (i < j0 + 3) s += expf(-d2);
  for (int off = 32; off; off >>= 1) s += __shfl_down(s, off, 64);
  __shared__ float part[4];
  const int lane = threadIdx.x & 63, w = threadIdx.x >> 6;
  if (lane == 0) part[w] = s;
  __syncthreads();
  if (threadIdx.x == 0) atomicAdd(accum, part[0] + part[1] + part[2] + part[3]);
}

__global__ void k_final(const float* __restrict__ accum, float* __restrict__ out) {
  const float n_pairs = (float)NROWS * (float)(NROWS - 1) * 0.5f;  // 523776
  out[0] = 0.25f * logf(accum[0] / n_pairs);
}

extern "C" void kernel_launch(void* const* d_in, const int* in_sizes, int n_in,
                              void* d_out, int out_size, void* d_ws, size_t ws_size,
                              hipStream_t stream) {
  const float* z = (const float*)d_in[0];
  float* out = (float*)d_out;
  char* ws = (char*)d_ws;

  float* inv_norm = (float*)(ws);           // 4 KB
  float* diag     = (float*)(ws + 4096);    // 4 KB
  float* accum    = (float*)(ws + 8192);    // 4 B
  float* gbuf     = (float*)(ws + 65536);   // slabs

  const size_t GB1 = (size_t)NROWS * NROWS * sizeof(float);  // 4 MB per slab
  const size_t BFB = (size_t)NROWS * KDIM * sizeof(ushort);  // 128 MB bf16 copy

  bool bf16src;
  int nslab;
  if (ws_size >= 65536 + 8 * GB1 + BFB)      { bf16src = true;  nslab = 8; }  // 160 MB (confirmed avail R1)
  else if (ws_size >= 65536 + 8 * GB1)       { bf16src = false; nslab = 8; }
  else                                       { bf16src = false; nslab = 1; }

  hipMemsetAsync(accum, 0, sizeof(float), stream);
  hipMemsetAsync(gbuf, 0, (size_t)nslab * GB1, stream);  // atomic accumulation needs zeroed slabs

  const void* gsrc = (const void*)z;
  if (bf16src) {
    ushort* zb = (ushort*)(ws + 65536 + (size_t)nslab * GB1);
    k_prep<<<NROWS, 256, 0, stream>>>(z, zb, inv_norm);
    gsrc = (const void*)zb;
  } else {
    k_rownorm<<<NROWS, 256, 0, stream>>>(z, inv_norm);
  }

  const int kPerSplit = KDIM / NSPLIT;  // 2048, NT=64
  dim3 grid(NTILE, NSPLIT);             // 36 x 32 = 1152 blocks (~4.5/CU)
  if (bf16src) k_gram<true ><<<grid, 256, 0, stream>>>(gsrc, gbuf, kPerSplit, nslab);
  else         k_gram<false><<<grid, 256, 0, stream>>>(gsrc, gbuf, kPerSplit, nslab);

  k_diag<<<NROWS / 256, 256, 0, stream>>>(gbuf, inv_norm, diag, nslab);
  k_expsum<<<(NROWS * NROWS / 4) / 256, 256, 0, stream>>>(gbuf, inv_norm, diag, accum, nslab);
  k_final<<<1, 1, 0, stream>>>(accum, out);
}

// Round 3
// 251.923 us; speedup vs baseline: 1.3525x; 1.2923x over previous
//
#include <hip/hip_runtime.h>
#include <hip/hip_bf16.h>
#include <stdint.h>

// DispersiveLoss: B=1024 rows, D=65536.
// R3: 256x256-tile 8-phase counted-vmcnt Gram GEMM (m201 structure, plain HIP):
//   16 tiles x 16 K-splits = 256 blocks (1/CU), 512 thr = 8 waves (2Mx4N),
//   BK=64, 128 KB dbuf LDS, st_16x32 XOR swizzle, raw s_barrier + vmcnt(6),
//   setprio around MFMA clusters. Epilogue: per-split fp32 slab (non-atomic)
//   or 8-slab 2-way atomic fallback if ws < 192 MB.

#define NROWS 1024
#define KDIM  65536
#define KSPLIT 16
#define KPS   (KDIM / KSPLIT)   // 4096 per block
#define BK    64
#define NKT   (KPS / BK)        // 64 K-tiles per block

typedef __attribute__((ext_vector_type(8))) short  s16x8;
typedef __attribute__((ext_vector_type(4))) float  f32x4;

#define AS1 __attribute__((address_space(1)))
#define AS3 __attribute__((address_space(3)))

__device__ __forceinline__ ushort f2bf(float f) {
  uint32_t u = __float_as_uint(f);
  return (ushort)((u + 0x7fffu + ((u >> 16) & 1u)) >> 16);  // RNE bf16
}

// ---- fused: row sum-of-squares -> inv_norm, plus raw fp32 -> bf16 cast ----
__global__ void k_prep(const float* __restrict__ z, ushort* __restrict__ zb,
                       float* __restrict__ inv_norm) {
  const int row = blockIdx.x;
  const float4* zr = (const float4*)(z + (size_t)row * KDIM);
  ushort* br = zb + (size_t)row * KDIM;
  float ss = 0.f;
  for (int i = threadIdx.x; i < KDIM / 4; i += blockDim.x) {
    const float4 v = zr[i];
    ss += v.x * v.x + v.y * v.y + v.z * v.z + v.w * v.w;
    ushort4 o;
    o.x = f2bf(v.x); o.y = f2bf(v.y); o.z = f2bf(v.z); o.w = f2bf(v.w);
    ((ushort4*)br)[i] = o;
  }
  for (int off = 32; off; off >>= 1) ss += __shfl_down(ss, off, 64);
  __shared__ float part[4];
  const int lane = threadIdx.x & 63, w = threadIdx.x >> 6;
  if (lane == 0) part[w] = ss;
  __syncthreads();
  if (threadIdx.x == 0) {
    const float t = part[0] + part[1] + part[2] + part[3];
    inv_norm[row] = 1.f / fmaxf(sqrtf(t), 1e-12f);
  }
}

// ---- 256^2 8-phase Gram GEMM ----
// LDS map (bytes): A[buf][half] = buf*32768 + half*16384        (0..65536)
//                  B[buf][half] = 65536 + buf*32768 + half*16384
// Within a half (128 rows x 64 bf16 cols): logical L = r*128 + c*2,
// physical P = L ^ (((L>>9)&1)<<5)   (st_16x32 swizzle, involution).
template <bool ATOMIC>
__global__ __launch_bounds__(512, 1)
void k_gram8(const ushort* __restrict__ zb, float* __restrict__ gout) {
  extern __shared__ char smem[];
  const int tid  = threadIdx.x;
  const int lane = tid & 63;
  const int wid  = tid >> 6;
  const int wr   = wid >> 2;     // 0..1  (M half)
  const int wc   = wid & 3;      // 0..3  (N quarter)
  const int t    = blockIdx.x;   // 0..15
  const int tm   = t >> 2, tn = t & 3;
  const int y    = blockIdx.y;   // K-split
  const size_t k0 = (size_t)y * KPS;

  const ushort* gA = zb + (size_t)(tm * 256) * KDIM + k0;
  const ushort* gB = zb + (size_t)(tn * 256) * KDIM + k0;

  // stage one 128x64 half-tile (16 KB) = 2 global_load_lds x 16B per thread.
  // LDS dest is linear P = q*8192 + tid*16 (wave-uniform base + lane*16);
  // global source is pre-swizzled with the same involution.
  auto stage_half = [&](const ushort* halfPanel, uint32_t ldsHalfBase, int kt) {
#pragma unroll
    for (int q = 0; q < 2; q++) {
      const uint32_t P = q * 8192u + (uint32_t)tid * 16u;
      const uint32_t L = P ^ (((P >> 9) & 1u) << 5);
      __builtin_amdgcn_global_load_lds(
          (const AS1 void*)((const char*)halfPanel + (size_t)(L >> 7) * (KDIM * 2)
                            + (L & 127u) + (size_t)kt * (BK * 2)),
          (AS3 void*)(smem + ldsHalfBase + P), 16, 0, 0);
    }
  };

  const uint32_t laneRB = (uint32_t)(lane & 15) * 128u + (uint32_t)(lane >> 4) * 16u;
  const uint32_t aBase = (uint32_t)wr * 16384u;
  const uint32_t bBase = 65536u + (uint32_t)(wc >> 1) * 16384u;
  const uint32_t bRowOff = (uint32_t)(wc & 1) * 64u * 128u;

  auto rdA = [&](uint32_t bo, int mi, int kk) -> s16x8 {
    uint32_t L = laneRB + (uint32_t)mi * 2048u + (uint32_t)kk * 64u;
    uint32_t P = L ^ (((L >> 9) & 1u) << 5);
    return *(const s16x8*)(smem + aBase + bo + P);
  };
  auto rdB = [&](uint32_t bo, int ni, int kk) -> s16x8 {
    uint32_t L = bRowOff + laneRB + (uint32_t)ni * 2048u + (uint32_t)kk * 64u;
    uint32_t P = L ^ (((L >> 9) & 1u) << 5);
    return *(const s16x8*)(smem + bBase + bo + P);
  };

  f32x4 acc[8][4];
#pragma unroll
  for (int m = 0; m < 8; m++)
#pragma unroll
    for (int n = 0; n < 4; n++) acc[m][n] = (f32x4){0.f, 0.f, 0.f, 0.f};

  // prologue: stage K-tiles 0 (buf0) and 1 (buf1), halves [B0,B1,A0,A1]
#pragma unroll
  for (int kt = 0; kt < 2; kt++) {
    const uint32_t bo = (uint32_t)kt * 32768u;
    stage_half(gB,              65536u + bo,           kt);
    stage_half(gB + 128 * KDIM, 65536u + bo + 16384u,  kt);
    stage_half(gA,              bo,                    kt);
    stage_half(gA + 128 * KDIM, bo + 16384u,           kt);
  }
  asm volatile("s_waitcnt vmcnt(6)" ::: "memory");  // tile 0 fully landed
  __builtin_amdgcn_s_barrier();

  s16x8 a[8][2], b[4][2];
  for (int T = 0; T < NKT; ++T) {
    const uint32_t bo = (uint32_t)(T & 1) * 32768u;
    const int S = T + 2;                 // stage target K-tile (same buf)
    const bool st = (S < NKT);

    // ---- phase 0: read B(8) + A m0,m1; stage B0'; MFMA m0,m1 ----
#pragma unroll
    for (int n = 0; n < 4; n++) { b[n][0] = rdB(bo, n, 0); b[n][1] = rdB(bo, n, 1); }
#pragma unroll
    for (int m = 0; m < 2; m++) { a[m][0] = rdA(bo, m, 0); a[m][1] = rdA(bo, m, 1); }
    if (st) stage_half(gB, 65536u + bo, S);
    __builtin_amdgcn_s_barrier();
    __builtin_amdgcn_s_setprio(1);
#pragma unroll
    for (int m = 0; m < 2; m++)
#pragma unroll
      for (int n = 0; n < 4; n++) {
        acc[m][n] = __builtin_amdgcn_mfma_f32_16x16x32_bf16(a[m][0], b[n][0], acc[m][n], 0, 0, 0);
        acc[m][n] = __builtin_amdgcn_mfma_f32_16x16x32_bf16(a[m][1], b[n][1], acc[m][n], 0, 0, 0);
      }
    __builtin_amdgcn_s_setprio(0);
    __builtin_amdgcn_s_barrier();

    // ---- phase 1: read A m2..7; stage B1'; MFMA m2,m3 ----
#pragma unroll
    for (int m = 2; m < 8; m++) { a[m][0] = rdA(bo, m, 0); a[m][1] = rdA(bo, m, 1); }
    if (st) stage_half(gB + 128 * KDIM, 65536u + bo + 16384u, S);
    __builtin_amdgcn_s_barrier();
    __builtin_amdgcn_s_setprio(1);
#pragma unroll
    for (int m = 2; m < 4; m++)
#pragma unroll
      for (int n = 0; n < 4; n++) {
        acc[m][n] = __builtin_amdgcn_mfma_f32_16x16x32_bf16(a[m][0], b[n][0], acc[m][n], 0, 0, 0);
        acc[m][n] = __builtin_amdgcn_mfma_f32_16x16x32_bf16(a[m][1], b[n][1], acc[m][n], 0, 0, 0);
      }
    __builtin_amdgcn_s_setprio(0);
    __builtin_amdgcn_s_barrier();

    // ---- phase 2: stage A0'; MFMA m4,m5 ----
    if (st) stage_half(gA, bo, S);
    __builtin_amdgcn_s_barrier();
    __builtin_amdgcn_s_setprio(1);
#pragma unroll
    for (int m = 4; m < 6; m++)
#pragma unroll
      for (int n = 0; n < 4; n++) {
        acc[m][n] = __builtin_amdgcn_mfma_f32_16x16x32_bf16(a[m][0], b[n][0], acc[m][n], 0, 0, 0);
        acc[m][n] = __builtin_amdgcn_mfma_f32_16x16x32_bf16(a[m][1], b[n][1], acc[m][n], 0, 0, 0);
      }
    __builtin_amdgcn_s_setprio(0);
    __builtin_amdgcn_s_barrier();

    // ---- phase 3: stage A1'; MFMA m6,m7; counted vmcnt; end barrier ----
    if (st) stage_half(gA + 128 * KDIM, bo + 16384u, S);
    __builtin_amdgcn_s_barrier();
    __builtin_amdgcn_s_setprio(1);
#pragma unroll
    for (int m = 6; m < 8; m++)
#pragma unroll
      for (int n = 0; n < 4; n++) {
        acc[m][n] = __builtin_amdgcn_mfma_f32_16x16x32_bf16(a[m][0], b[n][0], acc[m][n], 0, 0, 0);
        acc[m][n] = __builtin_amdgcn_mfma_f32_16x16x32_bf16(a[m][1], b[n][1], acc[m][n], 0, 0, 0);
      }
    __builtin_amdgcn_s_setprio(0);
    if (st) { asm volatile("s_waitcnt vmcnt(6)" ::: "memory"); }  // next tile landed, 3 halves in flight
    else    { asm volatile("s_waitcnt vmcnt(0)" ::: "memory"); }  // tail: drain (no stages this tile)
    __builtin_amdgcn_s_barrier();
  }

  // epilogue: C/D layout (m89): col = lane&15, row = (lane>>4)*4 + reg
  const int slab = ATOMIC ? (y & 7) : y;
  float* out = gout + (size_t)slab * ((size_t)NROWS * NROWS);
  const int r0 = tm * 256 + wr * 128 + ((lane >> 4) << 2);
  const int c0 = tn * 256 + wc * 64 + (lane & 15);
#pragma unroll
  for (int m = 0; m < 8; m++)
#pragma unroll
    for (int n = 0; n < 4; n++)
#pragma unroll
      for (int rg = 0; rg < 4; rg++) {
        const int R = r0 + m * 16 + rg;
        const int C = c0 + n * 16;
        if constexpr (ATOMIC)
          atomicAdd(&out[(size_t)R * NROWS + C], acc[m][n][rg]);
        else
          out[(size_t)R * NROWS + C] = acc[m][n][rg];
      }
}

// ---- diag_n[i] = (sum_s slab[s][i,i]) * inv_i^2 ----
__global__ void k_diag(const float* __restrict__ gbuf, const float* __restrict__ inv_norm,
                       float* __restrict__ diag, int nslab) {
  const int i = blockIdx.x * 256 + threadIdx.x;
  float s = 0.f;
  for (int q = 0; q < nslab; ++q)
    s += gbuf[(size_t)q * ((size_t)NROWS * NROWS) + (size_t)i * (NROWS + 1)];
  const float w = inv_norm[i];
  diag[i] = s * w * w;
}

// ---- accum = sum_{i!=j} exp(-max(d_i + d_j - 2 g_ij inv_i inv_j, 0)), full matrix ----
__global__ void k_expsum(const float* __restrict__ gbuf, const float* __restrict__ inv_norm,
                         const float* __restrict__ diag, float* __restrict__ accum, int nslab) {
  const int gid = blockIdx.x * 256 + threadIdx.x;
  const int e0 = gid * 4;
  const int i  = e0 >> 10;
  const int j0 = e0 & 1023;
  float gx = 0.f, gy = 0.f, gz = 0.f, gw = 0.f;
  for (int q = 0; q < nslab; ++q) {
    const float4 t = *(const float4*)(gbuf + (size_t)q * ((size_t)NROWS * NROWS) + e0);
    gx += t.x; gy += t.y; gz += t.z; gw += t.w;
  }
  const float wi = inv_norm[i];
  const float di = diag[i];
  const float4 wj = *(const float4*)(inv_norm + j0);
  const float4 dj = *(const float4*)(diag + j0);
  float s = 0.f;
  float gn, d2;
  gn = gx * wi * wj.x; d2 = fmaxf(di + dj.x - 2.f * gn, 0.f); if (i != j0 + 0) s += expf(-d2);
  gn = gy * wi * wj.y; d2 = fmaxf(di + dj.y - 2.f * gn, 0.f); if (i != j0 + 1) s += expf(-d2);
  gn = gz * wi * wj.z; d2 = fmaxf(di + dj.z - 2.f * gn, 0.f); if (i != j0 + 2) s += expf(-d2);
  gn = gw * wi * wj.w; d2 = fmaxf(di + dj.w - 2.f * gn, 0.f); if (i != j0 + 3) s += expf(-d2);
  for (int off = 32; off; off >>= 1) s += __shfl_down(s, off, 64);
  __shared__ float part[4];
  const int lane = threadIdx.x & 63, w = threadIdx.x >> 6;
  if (lane == 0) part[w] = s;
  __syncthreads();
  if (threadIdx.x == 0) atomicAdd(accum, part[0] + part[1] + part[2] + part[3]);
}

__global__ void k_final(const float* __restrict__ accum, float* __restrict__ out) {
  const float n_pairs = (float)NROWS * (float)(NROWS - 1);  // full off-diag count
  out[0] = 0.25f * logf(accum[0] / n_pairs);
}

extern "C" void kernel_launch(void* const* d_in, const int* in_sizes, int n_in,
                              void* d_out, int out_size, void* d_ws, size_t ws_size,
                              hipStream_t stream) {
  const float* z = (const float*)d_in[0];
  float* out = (float*)d_out;
  char* ws = (char*)d_ws;

  float* inv_norm = (float*)(ws);           // 4 KB
  float* diag     = (float*)(ws + 4096);    // 4 KB
  float* accum    = (float*)(ws + 8192);    // 4 B
  float* gbuf     = (float*)(ws + 65536);   // slabs

  const size_t GB1 = (size_t)NROWS * NROWS * sizeof(float);  // 4 MB per slab
  const size_t BFB = (size_t)NROWS * KDIM * sizeof(ushort);  // 128 MB bf16 copy

  bool atomic;
  int nslab;
  if (ws_size >= 65536 + 16 * GB1 + BFB) { atomic = false; nslab = 16; }  // 192 MB
  else                                   { atomic = true;  nslab = 8;  }  // 160 MB (proven fits)

  ushort* zbuf = (ushort*)(ws + 65536 + (size_t)nslab * GB1);

  hipMemsetAsync(accum, 0, sizeof(float), stream);
  if (atomic) hipMemsetAsync(gbuf, 0, (size_t)nslab * GB1, stream);

  k_prep<<<NROWS, 256, 0, stream>>>(z, zbuf, inv_norm);

  dim3 grid(16, KSPLIT);  // 16 tiles x 16 splits = 256 blocks, 1/CU
  if (!atomic) {
    hipFuncSetAttribute(reinterpret_cast<const void*>(&k_gram8<false>),
                        hipFuncAttributeMaxDynamicSharedMemorySize, 131072);
    k_gram8<false><<<grid, 512, 131072, stream>>>(zbuf, gbuf);
  } else {
    hipFuncSetAttribute(reinterpret_cast<const void*>(&k_gram8<true>),
                        hipFuncAttributeMaxDynamicSharedMemorySize, 131072);
    k_gram8<true><<<grid, 512, 131072, stream>>>(zbuf, gbuf);
  }

  k_diag<<<NROWS / 256, 256, 0, stream>>>(gbuf, inv_norm, diag, nslab);
  k_expsum<<<(NROWS * NROWS / 4) / 256, 256, 0, stream>>>(gbuf, inv_norm, diag, accum, nslab);
  k_final<<<1, 1, 0, stream>>>(accum, out);
}